// Round 1
// baseline (651.493 us; speedup 1.0000x reference)
//
#include <hip/hip_runtime.h>

typedef _Float16 half8 __attribute__((ext_vector_type(8)));
typedef float    f32x4 __attribute__((ext_vector_type(4)));

#define SMEM_BYTES 131072  // A: 2 x 32KiB (256x64 f16), W: 2 x 32KiB (256vc x 64k f16)

__device__ __forceinline__ float sigf(float x)  { return 1.0f / (1.0f + __expf(-x)); }
__device__ __forceinline__ float tanhf_(float x){ return 2.0f / (1.0f + __expf(-2.0f * x)) - 1.0f; }

__device__ __forceinline__ void gl_lds16(const void* g, void* l) {
  __builtin_amdgcn_global_load_lds(
      (const __attribute__((address_space(1))) unsigned int*)g,
      (__attribute__((address_space(3))) unsigned int*)l, 16, 0, 0);
}

// ---------------- prepack: fp32 weights -> f16 swizzled granules in ws ----------------
// W1 (gates):  [ht(4)][vcb(32)][kc(8)] 1KiB granules; vc = g*64+j (B^T form), K=512=[Wih|Whh]
// W2 (decomp): [ht(4)][jb(8)][kc(12)] granules; K=768 = [Wd_hi | Wd_lo | Wd_hi] (hi/lo split)
// granule-internal byte: ((row&7)*128 + kin*2) ^ ((row&7)<<4)  -- XOR bank swizzle baked in,
// so a linear global_load_lds copy reproduces the swizzled LDS image (both-sides rule).
__global__ __launch_bounds__(512) void prepack_kernel(
    const float* __restrict__ wih, const float* __restrict__ whh,
    const float* __restrict__ wd, char* __restrict__ wp)
{
  int idx = blockIdx.x * 512 + threadIdx.x;
  if (idx < (4 * 256 * 512)) {
    int k  = idx & 511;
    int vc = (idx >> 9) & 255;
    int ht = idx >> 17;
    int g = vc >> 6, j = vc & 63;
    int n = (g << 8) + (ht << 6) + j;                  // gate row in [4H]
    float v = (k < 256) ? wih[n * 256 + k] : whh[n * 256 + (k - 256)];
    int pos = ((((ht << 5) + (vc >> 3)) << 3) + (k >> 6)) * 1024
            + ((((vc & 7) << 7) + ((k & 63) << 1)) ^ ((vc & 7) << 4));
    *(_Float16*)(wp + pos) = (_Float16)v;
  } else {
    int i2 = idx - (4 * 256 * 512);
    int j = i2 & 63;
    int tmp = i2 >> 6;                                  // ht*768 + k
    int k = tmp % 768, ht = tmp / 768;
    int seg = k >> 8, kc = k & 255;
    float v = wd[kc * 256 + (ht << 6) + j];             // cx @ W_decomp: W indexed [k][h]
    _Float16 hi = (_Float16)v;
    _Float16 val = (seg == 1) ? (_Float16)(v - (float)hi) : hi;
    int pos = (1 << 20)
            + ((((ht << 3) + (j >> 3)) * 12) + (k >> 6)) * 1024
            + ((((j & 7) << 7) + ((k & 63) << 1)) ^ ((j & 7) << 4));
    *(_Float16*)(wp + pos) = val;
  }
}

// ---------------- fused TA-LSTM cell ----------------
// block: 512 thr (8 waves), tile 256 rows x 64 h.  Virtual cols: 4 gates x 64 + 64 decomp.
// wave (mw=w>>1, cw=w&1): rows mw*64..+64, j-slice cw*32..+32 -> epilogue self-contained.
// K-chunks (BK=64): cc 0..3 input, 4..7 hx  (gates, 1-pass f16)
//                   cc 8..15 cx_hi, 16..19 cx_lo (decomp hi/lo x [Whi|Wlo|Whi], 3-pass)
__global__ __launch_bounds__(512, 2) void talstm_kernel(
    const float* __restrict__ inp, const float* __restrict__ tt,
    const float* __restrict__ hx,  const float* __restrict__ cx,
    const float* __restrict__ bih, const float* __restrict__ bhh,
    const float* __restrict__ bd,  const char* __restrict__ wp,
    float* __restrict__ out)
{
  extern __shared__ __align__(16) char smem[];
  const int tid  = threadIdx.x;
  const int w    = tid >> 6;
  const int lane = tid & 63;
  const int mt   = blockIdx.x >> 2;
  const int ht   = blockIdx.x & 3;
  const int mbase = mt << 8;
  const int mw = w >> 1, cw = w & 1;

  f32x4 acc1[4][4][2];   // [Mt][gate][jc]
  f32x4 acc2[4][2];      // [Mt][jc]
  const f32x4 fzero = {0.f, 0.f, 0.f, 0.f};
#pragma unroll
  for (int m = 0; m < 4; ++m) {
#pragma unroll
    for (int g = 0; g < 4; ++g) { acc1[m][g][0] = fzero; acc1[m][g][1] = fzero; }
    acc2[m][0] = fzero; acc2[m][1] = fzero;
  }

  const int arow = tid >> 1;            // 0..255 staging row
  const int ac0  = (tid & 1) << 5;      // 0 / 32 (k within chunk)
  const int aswz = (arow & 7) << 4;

  auto a_src = [&](int cc) -> const float* {
    const float* s = (cc < 4) ? inp : (cc < 8 ? hx : cx);
    return s + (size_t)(mbase + arow) * 256 + ((cc & 3) << 6) + ac0;
  };

  auto stage_w = [&](int cc, int buf) {
    char* wdst = smem + 65536 + (buf << 15);
    if (cc < 8) {
#pragma unroll
      for (int it = 0; it < 4; ++it) {
        int vcb = (w << 2) + it;
        const char* g = wp + (((((ht << 5) + vcb) << 3) + cc) << 10) + (lane << 4);
        gl_lds16(g, wdst + (vcb << 10));
      }
    } else {
      const char* g = wp + (1 << 20) + (((((ht << 3) + w) * 12) + (cc - 8)) << 10) + (lane << 4);
      gl_lds16(g, wdst + (w << 10));
    }
  };

  auto a_write = [&](int ccn, int buf, const f32x4 (&v)[8]) {
    char* Ad = smem + (buf << 15);
#pragma unroll
    for (int q = 0; q < 4; ++q) {
      half8 hv;
#pragma unroll
      for (int e = 0; e < 4; ++e) {
        float f0 = v[2 * q][e], f1 = v[2 * q + 1][e];
        if (ccn >= 16) {                       // lo part of cx
          _Float16 h0 = (_Float16)f0; f0 -= (float)h0;
          _Float16 h1 = (_Float16)f1; f1 -= (float)h1;
        }
        hv[e]     = (_Float16)f0;
        hv[e + 4] = (_Float16)f1;
      }
      int byte = ((arow << 7) + ((ac0 + (q << 3)) << 1)) ^ aswz;
      *(half8*)(Ad + byte) = hv;
    }
  };

  const int l15 = lane & 15;
  const int lk  = (lane >> 4) << 3;

  auto compute = [&](int cc, int buf) {
    const char* Ab = smem + (buf << 15);
    const char* Wb = smem + 65536 + (buf << 15);
#pragma unroll
    for (int kk = 0; kk < 2; ++kk) {
      const int kb = (((kk << 5) + lk) << 1);
      half8 af[4];
#pragma unroll
      for (int m = 0; m < 4; ++m) {
        int r = (mw << 6) + (m << 4) + l15;
        af[m] = *(const half8*)(Ab + (((r << 7) + kb) ^ ((r & 7) << 4)));
      }
      if (cc < 8) {
#pragma unroll
        for (int g = 0; g < 4; ++g) {
#pragma unroll
          for (int jc = 0; jc < 2; ++jc) {
            int vc = (g << 6) + (cw << 5) + (jc << 4) + l15;
            half8 bf = *(const half8*)(Wb + (((vc << 7) + kb) ^ ((vc & 7) << 4)));
#pragma unroll
            for (int m = 0; m < 4; ++m)
              acc1[m][g][jc] = __builtin_amdgcn_mfma_f32_16x16x32_f16(af[m], bf, acc1[m][g][jc], 0, 0, 0);
          }
        }
      } else {
#pragma unroll
        for (int jc = 0; jc < 2; ++jc) {
          int vc = (cw << 5) + (jc << 4) + l15;
          half8 bf = *(const half8*)(Wb + (((vc << 7) + kb) ^ ((vc & 7) << 4)));
#pragma unroll
          for (int m = 0; m < 4; ++m)
            acc2[m][jc] = __builtin_amdgcn_mfma_f32_16x16x32_f16(af[m], bf, acc2[m][jc], 0, 0, 0);
        }
      }
    }
  };

  // prologue: stage chunk 0 into buf 0
  {
    stage_w(0, 0);
    const float* s = a_src(0);
    f32x4 v[8];
#pragma unroll
    for (int q = 0; q < 8; ++q) v[q] = *(const f32x4*)(s + (q << 2));
    a_write(0, 0, v);
  }
  __syncthreads();

#pragma unroll 1
  for (int cc = 0; cc < 20; ++cc) {
    const int cur = cc & 1, nxt = cur ^ 1;
    f32x4 v[8];
    if (cc < 19) {                      // issue next-chunk loads early (hide HBM latency)
      const float* s = a_src(cc + 1);
#pragma unroll
      for (int q = 0; q < 8; ++q) v[q] = *(const f32x4*)(s + (q << 2));
      stage_w(cc + 1, nxt);
    }
    compute(cc, cur);
    if (cc < 19) a_write(cc + 1, nxt, v);
    __syncthreads();
  }

  // ---------------- epilogue ----------------
  const int e4 = (lane >> 4) << 2;
  const int hb = (ht << 6) + (cw << 5) + l15;
  const int rb = mbase + (mw << 6) + e4;
#pragma unroll
  for (int jc = 0; jc < 2; ++jc) {
    const int h = hb + (jc << 4);
    const float bi  = bih[h]       + bhh[h];
    const float bf_ = bih[256 + h] + bhh[256 + h];
    const float bg  = bih[512 + h] + bhh[512 + h];
    const float bo  = bih[768 + h] + bhh[768 + h];
    const float bdv = bd[h];
#pragma unroll
    for (int m = 0; m < 4; ++m) {
#pragma unroll
      for (int e = 0; e < 4; ++e) {
        const int r = rb + (m << 4) + e;
        const float tv = tt[r];
        const float T = (tv != 0.0f) ? (1.0f / tv) : 0.0f;
        const float cxv = cx[(size_t)r * 256 + h];
        const float gi = sigf (acc1[m][0][jc][e] + bi);
        const float gf = sigf (acc1[m][1][jc][e] + bf_);
        const float gg = tanhf_(acc1[m][2][jc][e] + bg);
        const float go = sigf (acc1[m][3][jc][e] + bo);
        const float cst = tanhf_(acc2[m][jc][e] + bdv);
        const float cxa = cxv - cst + T * cst;
        const float cy = gf * cxa + gi * gg;
        const float hy = go * tanhf_(cy);
        out[(size_t)r * 256 + h] = hy;
        out[(size_t)16777216 + (size_t)r * 256 + h] = cy;
      }
    }
  }
}

extern "C" void kernel_launch(void* const* d_in, const int* in_sizes, int n_in,
                              void* d_out, int out_size, void* d_ws, size_t ws_size,
                              hipStream_t stream) {
  const float* inp = (const float*)d_in[0];
  const float* t   = (const float*)d_in[1];
  const float* hx  = (const float*)d_in[2];
  const float* cx  = (const float*)d_in[3];
  const float* wih = (const float*)d_in[4];
  const float* whh = (const float*)d_in[5];
  const float* bih = (const float*)d_in[6];
  const float* bhh = (const float*)d_in[7];
  const float* wd  = (const float*)d_in[8];
  const float* bd  = (const float*)d_in[9];
  float* out = (float*)d_out;
  char* wp = (char*)d_ws;   // needs 1.375 MiB: 1 MiB W1 + 384 KiB W2

  prepack_kernel<<<1408, 512, 0, stream>>>(wih, whh, wd, wp);

  hipFuncSetAttribute((const void*)talstm_kernel,
                      hipFuncAttributeMaxDynamicSharedMemorySize, SMEM_BYTES);
  talstm_kernel<<<1024, 512, SMEM_BYTES, stream>>>(inp, t, hx, cx, bih, bhh, bd, wp, out);
}

// Round 2
// 325.682 us; speedup vs baseline: 2.0004x; 2.0004x over previous
//
#include <hip/hip_runtime.h>

typedef _Float16 half8 __attribute__((ext_vector_type(8)));
typedef float    f32x4 __attribute__((ext_vector_type(4)));

#define LDS_BYTES (65536 + 256)   // A tile 32x1024 f16 + t tile

__device__ __forceinline__ float sigf(float x)  { return 1.0f / (1.0f + __expf(-x)); }
__device__ __forceinline__ float tanhf_(float x){ return 2.0f / (1.0f + __expf(-2.0f * x)) - 1.0f; }

// ---------------- prepack: fp32 weights -> f16 MFMA-fragment granules in ws ----------------
// Gate granules (1 MiB @ wp+0): id = ((g*16 + h>>4)*16 + kslice), 1 KiB each.
//   Lane l of a wave reads byte l*16: element e = W[g*256 + (h0 + (l&15))][ks*32 + (l>>4)*8 + e]
//   (K = 512 = [Wih | Whh]).
// Decomp granules (128 KiB @ wp+1MiB): id = ((h>>4)*8 + kslice), value = Wd[k][h] (f16 hi only;
//   lo correction comes from splitting cx, reusing the SAME B fragment for both passes).
__global__ __launch_bounds__(512) void prepack_kernel(
    const float* __restrict__ wih, const float* __restrict__ whh,
    const float* __restrict__ wd, char* __restrict__ wp)
{
  int idx = blockIdx.x * 512 + threadIdx.x;
  if (idx < 65536) {                       // gates: 8 consecutive k per thread
    int n  = idx >> 6;                     // 0..1023 = g*256 + h
    int k8 = (idx & 63) << 3;              // 0..504
    const float* src = (k8 < 256) ? (wih + n * 256 + k8) : (whh + n * 256 + (k8 - 256));
    f32x4 v0 = *(const f32x4*)src;
    f32x4 v1 = *(const f32x4*)(src + 4);
    half8 hv;
#pragma unroll
    for (int e = 0; e < 4; ++e) { hv[e] = (_Float16)v0[e]; hv[e + 4] = (_Float16)v1[e]; }
    int g = n >> 8, h = n & 255;
    int gran = (((g << 4) + (h >> 4)) << 4) + (k8 >> 5);
    int lane = (h & 15) + (((k8 >> 3) & 3) << 4);
    *(half8*)(wp + (gran << 10) + (lane << 4)) = hv;
  } else {                                 // decomp: scalar (coalesced reads over h)
    int i2 = idx - 65536;
    int h = i2 & 255, k = i2 >> 8;
    float v = wd[k * 256 + h];
    int gran = ((h >> 4) << 3) + (k >> 5);
    int lane = (h & 15) + (((k >> 3) & 3) << 4);
    *(_Float16*)(wp + (1 << 20) + (gran << 10) + (lane << 4) + ((k & 7) << 1)) = (_Float16)v;
  }
}

// ---------------- fused TA-LSTM cell ----------------
// Block: 512 thr (8 waves), tile = 32 rows x FULL 256 h  -> zero A duplication.
// LDS: A staged ONCE as f16 [32 rows][1024 k] = input(0..255)|hx(256..511)|cx_hi(512..767)|cx_lo(768..1023),
//      XOR-swizzled (byte ^= (row&7)<<4). ONE barrier; then waves stream W fragments from L2.
// Wave w owns h-slice [w*32, w*32+32): acc[4 gates][2 jc][2 m] + accd[2][2] = 80 VGPRs.
__global__ __launch_bounds__(512, 2) void talstm_kernel(
    const float* __restrict__ inp, const float* __restrict__ tt,
    const float* __restrict__ hx,  const float* __restrict__ cx,
    const float* __restrict__ bih, const float* __restrict__ bhh,
    const float* __restrict__ bd,  const char* __restrict__ wp,
    float* __restrict__ out)
{
  extern __shared__ __align__(16) char smem[];
  float* tsh = (float*)(smem + 65536);
  const int tid  = threadIdx.x;
  const int lane = tid & 63;
  const int w    = tid >> 6;               // wave id = h-slice
  const int rbase = blockIdx.x << 5;       // 32 rows/block

  if (tid < 32) tsh[tid] = tt[rbase + tid];

  // ---- stage A (once) ----
  const int srow = tid >> 4;               // 0..31
  const int sc0  = (tid & 15) << 4;        // 16 floats per thread per section
  const int swz  = (srow & 7) << 4;
  const size_t rowoff = (size_t)(rbase + srow) * 256 + sc0;

  auto stage16 = [&](const float* src, int kbase, bool split) {
    f32x4 v[4];
#pragma unroll
    for (int q = 0; q < 4; ++q) v[q] = *(const f32x4*)(src + (q << 2));
    half8 hi0, hi1;
#pragma unroll
    for (int e = 0; e < 4; ++e) {
      hi0[e] = (_Float16)v[0][e]; hi0[e + 4] = (_Float16)v[1][e];
      hi1[e] = (_Float16)v[2][e]; hi1[e + 4] = (_Float16)v[3][e];
    }
    int b0 = (srow << 11) + ((kbase + sc0) << 1);
    *(half8*)(smem + ((b0     ) ^ swz)) = hi0;
    *(half8*)(smem + ((b0 + 16) ^ swz)) = hi1;
    if (split) {                           // cx residual -> k + 256
      half8 lo0, lo1;
#pragma unroll
      for (int e = 0; e < 4; ++e) {
        lo0[e]     = (_Float16)(v[0][e] - (float)hi0[e]);
        lo0[e + 4] = (_Float16)(v[1][e] - (float)hi0[e + 4]);
        lo1[e]     = (_Float16)(v[2][e] - (float)hi1[e]);
        lo1[e + 4] = (_Float16)(v[3][e] - (float)hi1[e + 4]);
      }
      int b1 = b0 + 512;
      *(half8*)(smem + ((b1     ) ^ swz)) = lo0;
      *(half8*)(smem + ((b1 + 16) ^ swz)) = lo1;
    }
  };
  stage16(inp + rowoff,   0, false);
  stage16(hx  + rowoff, 256, false);
  stage16(cx  + rowoff, 512, true);
  __syncthreads();

  // ---- main compute: stream W fragments from L2, A fragments from LDS ----
  f32x4 acc[4][2][2];                      // [gate][jc][m]
  f32x4 accd[2][2];                        // [jc][m]
  const f32x4 fz = {0.f, 0.f, 0.f, 0.f};
#pragma unroll
  for (int g = 0; g < 4; ++g)
#pragma unroll
    for (int jc = 0; jc < 2; ++jc) { acc[g][jc][0] = fz; acc[g][jc][1] = fz; }
  accd[0][0] = fz; accd[0][1] = fz; accd[1][0] = fz; accd[1][1] = fz;

  const int l15 = lane & 15;
  const int lkB = (lane >> 4) << 4;        // (lane>>4)*8 elems * 2B
  const int rsw = (l15 & 7) << 4;          // row swizzle (rows m*16+l15 share row&7)
  const int a0b = (l15 << 11) + lkB;       // row l15
  const int a1b = ((16 + l15) << 11) + lkB;// row 16+l15
  auto afrag = [&](int base, int k) -> half8 {
    return *(const half8*)(smem + ((base + (k << 1)) ^ rsw));
  };

  const char* wg  = wp;
  const char* wdd = wp + (1 << 20);
  const int laneB = lane << 4;
  const int hb0   = w << 1;                // h-block of jc=0

#pragma unroll
  for (int s = 0; s < 16; ++s) {           // gates: K = 512
    half8 a0 = afrag(a0b, s << 5);
    half8 a1 = afrag(a1b, s << 5);
#pragma unroll
    for (int g = 0; g < 4; ++g) {
#pragma unroll
      for (int jc = 0; jc < 2; ++jc) {
        half8 b = *(const half8*)(wg + (((((g << 4) + hb0 + jc) << 4) + s) << 10) + laneB);
        acc[g][jc][0] = __builtin_amdgcn_mfma_f32_16x16x32_f16(a0, b, acc[g][jc][0], 0, 0, 0);
        acc[g][jc][1] = __builtin_amdgcn_mfma_f32_16x16x32_f16(a1, b, acc[g][jc][1], 0, 0, 0);
      }
    }
  }
#pragma unroll
  for (int s = 0; s < 8; ++s) {            // decomp: K = 256, hi+lo passes share B frag
    half8 h0 = afrag(a0b, 512 + (s << 5));
    half8 h1 = afrag(a1b, 512 + (s << 5));
    half8 l0 = afrag(a0b, 768 + (s << 5));
    half8 l1 = afrag(a1b, 768 + (s << 5));
#pragma unroll
    for (int jc = 0; jc < 2; ++jc) {
      half8 b = *(const half8*)(wdd + ((((hb0 + jc) << 3) + s) << 10) + laneB);
      accd[jc][0] = __builtin_amdgcn_mfma_f32_16x16x32_f16(h0, b, accd[jc][0], 0, 0, 0);
      accd[jc][0] = __builtin_amdgcn_mfma_f32_16x16x32_f16(l0, b, accd[jc][0], 0, 0, 0);
      accd[jc][1] = __builtin_amdgcn_mfma_f32_16x16x32_f16(h1, b, accd[jc][1], 0, 0, 0);
      accd[jc][1] = __builtin_amdgcn_mfma_f32_16x16x32_f16(l1, b, accd[jc][1], 0, 0, 0);
    }
  }

  // ---- epilogue ----
  const int er = (lane >> 4) << 2;         // C/D row = (lane>>4)*4 + e
#pragma unroll
  for (int jc = 0; jc < 2; ++jc) {
    const int h   = (w << 5) + (jc << 4) + l15;
    const float bi  = bih[h]       + bhh[h];
    const float bfg = bih[256 + h] + bhh[256 + h];
    const float bg  = bih[512 + h] + bhh[512 + h];
    const float bo  = bih[768 + h] + bhh[768 + h];
    const float bdv = bd[h];
    const int hB = (512 + h) << 1;         // cx_hi byte offset within a row
#pragma unroll
    for (int m = 0; m < 2; ++m) {
#pragma unroll
      for (int e = 0; e < 4; ++e) {
        const int rl = (m << 4) + er + e;
        const int r  = rbase + rl;
        const float tv = tsh[rl];
        const float T  = (tv != 0.0f) ? (1.0f / tv) : 0.0f;
        const int cb  = rl << 11;
        const int csw = (rl & 7) << 4;
        const float cxv = (float)*(const _Float16*)(smem + ((cb + hB      ) ^ csw))
                        + (float)*(const _Float16*)(smem + ((cb + hB + 512) ^ csw));
        const float gi  = sigf  (acc[0][jc][m][e] + bi);
        const float gf  = sigf  (acc[1][jc][m][e] + bfg);
        const float gg  = tanhf_(acc[2][jc][m][e] + bg);
        const float go  = sigf  (acc[3][jc][m][e] + bo);
        const float cst = tanhf_(accd[jc][m][e] + bdv);
        const float cxa = cxv - cst + T * cst;
        const float cy  = gf * cxa + gi * gg;
        const float hy  = go * tanhf_(cy);
        out[(size_t)r * 256 + h]               = hy;
        out[16777216ull + (size_t)r * 256 + h] = cy;
      }
    }
  }
}

extern "C" void kernel_launch(void* const* d_in, const int* in_sizes, int n_in,
                              void* d_out, int out_size, void* d_ws, size_t ws_size,
                              hipStream_t stream) {
  const float* inp = (const float*)d_in[0];
  const float* t   = (const float*)d_in[1];
  const float* hx  = (const float*)d_in[2];
  const float* cx  = (const float*)d_in[3];
  const float* wih = (const float*)d_in[4];
  const float* whh = (const float*)d_in[5];
  const float* bih = (const float*)d_in[6];
  const float* bhh = (const float*)d_in[7];
  const float* wd  = (const float*)d_in[8];
  const float* bd  = (const float*)d_in[9];
  float* out = (float*)d_out;
  char* wp = (char*)d_ws;   // 1.125 MiB: 1 MiB gate granules + 128 KiB decomp granules

  prepack_kernel<<<256, 512, 0, stream>>>(wih, whh, wd, wp);

  hipFuncSetAttribute((const void*)talstm_kernel,
                      hipFuncAttributeMaxDynamicSharedMemorySize, LDS_BYTES);
  talstm_kernel<<<2048, 512, LDS_BYTES, stream>>>(inp, t, hx, cx, bih, bhh, bd, wp, out);
}

// Round 3
// 176.516 us; speedup vs baseline: 3.6909x; 1.8451x over previous
//
#include <hip/hip_runtime.h>

typedef _Float16 half8 __attribute__((ext_vector_type(8)));
typedef float    f32x4 __attribute__((ext_vector_type(4)));

#define LDS_BYTES (131072 + 256)   // A tile 64x1024 f16 (swizzled) + t tile

__device__ __forceinline__ float sigf(float x)  { return 1.0f / (1.0f + __expf(-x)); }
__device__ __forceinline__ float tanhf_(float x){ return 2.0f / (1.0f + __expf(-2.0f * x)) - 1.0f; }

// ---------------- prepack: fp32 weights -> f16 MFMA-fragment granules in ws ----------------
// Gate granules (1 MiB @ wp+0): id = ((g*16 + h>>4)*16 + kslice), 1 KiB each.
//   Lane l reads byte l*16: element e = W[g*256 + (h0 + (l&15))][ks*32 + (l>>4)*8 + e]
//   (K = 512 = [Wih | Whh]).
// Decomp granules (128 KiB @ wp+1MiB): id = ((h>>4)*8 + kslice), value = Wd[k][h] (f16 hi;
//   lo correction comes from splitting cx, reusing the SAME B fragment for both passes).
__global__ __launch_bounds__(512) void prepack_kernel(
    const float* __restrict__ wih, const float* __restrict__ whh,
    const float* __restrict__ wd, char* __restrict__ wp)
{
  int idx = blockIdx.x * 512 + threadIdx.x;
  if (idx < 65536) {                       // gates: 8 consecutive k per thread
    int n  = idx >> 6;                     // 0..1023 = g*256 + h
    int k8 = (idx & 63) << 3;              // 0..504
    const float* src = (k8 < 256) ? (wih + n * 256 + k8) : (whh + n * 256 + (k8 - 256));
    f32x4 v0 = *(const f32x4*)src;
    f32x4 v1 = *(const f32x4*)(src + 4);
    half8 hv;
#pragma unroll
    for (int e = 0; e < 4; ++e) { hv[e] = (_Float16)v0[e]; hv[e + 4] = (_Float16)v1[e]; }
    int g = n >> 8, h = n & 255;
    int gran = (((g << 4) + (h >> 4)) << 4) + (k8 >> 5);
    int lane = (h & 15) + (((k8 >> 3) & 3) << 4);
    *(half8*)(wp + (gran << 10) + (lane << 4)) = hv;
  } else {                                 // decomp: scalar (coalesced reads over h)
    int i2 = idx - 65536;
    int h = i2 & 255, k = i2 >> 8;
    float v = wd[k * 256 + h];
    int gran = ((h >> 4) << 3) + (k >> 5);
    int lane = (h & 15) + (((k >> 3) & 3) << 4);
    *(_Float16*)(wp + (1 << 20) + (gran << 10) + (lane << 4) + ((k & 7) << 1)) = (_Float16)v;
  }
}

// ---------------- fused TA-LSTM cell ----------------
// Block: 1024 thr (16 waves), tile = 64 rows x FULL 256 h -> A read once, zero duplication.
// LDS: A staged ONCE as f16 [64 rows][1024 k] = input|hx|cx_hi|cx_lo, XOR-swizzled
//      (byte ^= (row&7)<<4). ONE barrier; then waves stream W fragments from L2.
// Wave w owns 64 rows x 16 h (h-slice w): acc[4 gates][4 m] + accd[4 m] = 80 VGPRs.
// 72 W-fragment loads per wave (B-frag reused across 4 m-strips), 16 waves/CU resident.
__global__ __launch_bounds__(1024, 4) void talstm_kernel(
    const float* __restrict__ inp, const float* __restrict__ tt,
    const float* __restrict__ hx,  const float* __restrict__ cx,
    const float* __restrict__ bih, const float* __restrict__ bhh,
    const float* __restrict__ bd,  const char* __restrict__ wp,
    float* __restrict__ out)
{
  extern __shared__ __align__(16) char smem[];
  float* tsh = (float*)(smem + 131072);
  const int tid  = threadIdx.x;
  const int lane = tid & 63;
  const int w    = tid >> 6;               // wave id = h-slice (0..15)
  const int rbase = blockIdx.x << 6;       // 64 rows/block

  if (tid < 64) tsh[tid] = tt[rbase + tid];

  // ---- stage A (once) ----
  const int srow = tid >> 4;               // 0..63
  const int sc0  = (tid & 15) << 4;        // 16 floats per thread per section
  const int swz  = (srow & 7) << 4;
  const size_t rowoff = (size_t)(rbase + srow) * 256 + sc0;

  auto stage16 = [&](const float* src, int kbase, bool split) {
    f32x4 v[4];
#pragma unroll
    for (int q = 0; q < 4; ++q) v[q] = *(const f32x4*)(src + (q << 2));
    half8 hi0, hi1;
#pragma unroll
    for (int e = 0; e < 4; ++e) {
      hi0[e] = (_Float16)v[0][e]; hi0[e + 4] = (_Float16)v[1][e];
      hi1[e] = (_Float16)v[2][e]; hi1[e + 4] = (_Float16)v[3][e];
    }
    int b0 = (srow << 11) + ((kbase + sc0) << 1);
    *(half8*)(smem + ((b0     ) ^ swz)) = hi0;
    *(half8*)(smem + ((b0 + 16) ^ swz)) = hi1;
    if (split) {                           // cx residual -> k + 256
      half8 lo0, lo1;
#pragma unroll
      for (int e = 0; e < 4; ++e) {
        lo0[e]     = (_Float16)(v[0][e] - (float)hi0[e]);
        lo0[e + 4] = (_Float16)(v[1][e] - (float)hi0[e + 4]);
        lo1[e]     = (_Float16)(v[2][e] - (float)hi1[e]);
        lo1[e + 4] = (_Float16)(v[3][e] - (float)hi1[e + 4]);
      }
      int b1 = b0 + 512;
      *(half8*)(smem + ((b1     ) ^ swz)) = lo0;
      *(half8*)(smem + ((b1 + 16) ^ swz)) = lo1;
    }
  };
  stage16(inp + rowoff,   0, false);
  stage16(hx  + rowoff, 256, false);
  stage16(cx  + rowoff, 512, true);
  __syncthreads();

  // ---- main compute: stream W fragments from L2, A fragments from LDS ----
  f32x4 acc[4][4];                         // [gate][m-strip]
  f32x4 accd[4];                           // [m-strip]
  const f32x4 fz = {0.f, 0.f, 0.f, 0.f};
#pragma unroll
  for (int g = 0; g < 4; ++g)
#pragma unroll
    for (int m = 0; m < 4; ++m) acc[g][m] = fz;
#pragma unroll
  for (int m = 0; m < 4; ++m) accd[m] = fz;

  const int l15 = lane & 15;
  const int lkB = (lane >> 4) << 4;        // (lane>>4)*8 elems * 2B
  const int rsw = (l15 & 7) << 4;          // row swizzle (rows m*16+l15 share row&7)
  int abase[4];
#pragma unroll
  for (int m = 0; m < 4; ++m) abase[m] = (((m << 4) + l15) << 11) + lkB;
  auto afrag = [&](int m, int k) -> half8 {
    return *(const half8*)(smem + ((abase[m] + (k << 1)) ^ rsw));
  };

  const char* wg0 = wp + (size_t)((w << 4) << 10);          // g=0 granule run (16 KiB)
  const char* wdd = wp + (1 << 20) + (size_t)((w << 3) << 10);
  const int laneB = lane << 4;

#pragma unroll
  for (int s = 0; s < 16; ++s) {           // gates: K = 512
    half8 b0 = *(const half8*)(wg0 + (s << 10)             + laneB);
    half8 b1 = *(const half8*)(wg0 + (s << 10) + (1 << 18) + laneB);  // g=1: +256 KiB
    half8 b2 = *(const half8*)(wg0 + (s << 10) + (2 << 18) + laneB);
    half8 b3 = *(const half8*)(wg0 + (s << 10) + (3 << 18) + laneB);
#pragma unroll
    for (int m = 0; m < 4; ++m) {
      half8 a = afrag(m, s << 5);
      acc[0][m] = __builtin_amdgcn_mfma_f32_16x16x32_f16(a, b0, acc[0][m], 0, 0, 0);
      acc[1][m] = __builtin_amdgcn_mfma_f32_16x16x32_f16(a, b1, acc[1][m], 0, 0, 0);
      acc[2][m] = __builtin_amdgcn_mfma_f32_16x16x32_f16(a, b2, acc[2][m], 0, 0, 0);
      acc[3][m] = __builtin_amdgcn_mfma_f32_16x16x32_f16(a, b3, acc[3][m], 0, 0, 0);
    }
  }
#pragma unroll
  for (int s = 0; s < 8; ++s) {            // decomp: K = 256, hi+lo share the B frag
    half8 b = *(const half8*)(wdd + (s << 10) + laneB);
#pragma unroll
    for (int m = 0; m < 4; ++m) {
      half8 ah = afrag(m, 512 + (s << 5));
      half8 al = afrag(m, 768 + (s << 5));
      accd[m] = __builtin_amdgcn_mfma_f32_16x16x32_f16(ah, b, accd[m], 0, 0, 0);
      accd[m] = __builtin_amdgcn_mfma_f32_16x16x32_f16(al, b, accd[m], 0, 0, 0);
    }
  }

  // ---- epilogue ----
  const int er = (lane >> 4) << 2;         // C/D row = (lane>>4)*4 + e
  const int h  = (w << 4) + l15;
  const float bi  = bih[h]       + bhh[h];
  const float bfg = bih[256 + h] + bhh[256 + h];
  const float bg  = bih[512 + h] + bhh[512 + h];
  const float bo  = bih[768 + h] + bhh[768 + h];
  const float bdv = bd[h];
  const int hB = (512 + h) << 1;           // cx_hi byte offset within a row
#pragma unroll
  for (int m = 0; m < 4; ++m) {
#pragma unroll
    for (int e = 0; e < 4; ++e) {
      const int rl = (m << 4) + er + e;
      const int r  = rbase + rl;
      const float tv = tsh[rl];
      const float T  = (tv != 0.0f) ? (1.0f / tv) : 0.0f;
      const int cb  = rl << 11;
      const int csw = (rl & 7) << 4;
      const float cxv = (float)*(const _Float16*)(smem + ((cb + hB      ) ^ csw))
                      + (float)*(const _Float16*)(smem + ((cb + hB + 512) ^ csw));
      const float gi  = sigf  (acc[0][m][e] + bi);
      const float gf  = sigf  (acc[1][m][e] + bfg);
      const float gg  = tanhf_(acc[2][m][e] + bg);
      const float go  = sigf  (acc[3][m][e] + bo);
      const float cst = tanhf_(accd[m][e] + bdv);
      const float cxa = cxv - cst + T * cst;
      const float cy  = gf * cxa + gi * gg;
      const float hy  = go * tanhf_(cy);
      out[(size_t)r * 256 + h]               = hy;
      out[16777216ull + (size_t)r * 256 + h] = cy;
    }
  }
}

extern "C" void kernel_launch(void* const* d_in, const int* in_sizes, int n_in,
                              void* d_out, int out_size, void* d_ws, size_t ws_size,
                              hipStream_t stream) {
  const float* inp = (const float*)d_in[0];
  const float* t   = (const float*)d_in[1];
  const float* hx  = (const float*)d_in[2];
  const float* cx  = (const float*)d_in[3];
  const float* wih = (const float*)d_in[4];
  const float* whh = (const float*)d_in[5];
  const float* bih = (const float*)d_in[6];
  const float* bhh = (const float*)d_in[7];
  const float* wd  = (const float*)d_in[8];
  const float* bd  = (const float*)d_in[9];
  float* out = (float*)d_out;
  char* wp = (char*)d_ws;   // 1.125 MiB: 1 MiB gate granules + 128 KiB decomp granules

  prepack_kernel<<<256, 512, 0, stream>>>(wih, whh, wd, wp);

  hipFuncSetAttribute((const void*)talstm_kernel,
                      hipFuncAttributeMaxDynamicSharedMemorySize, LDS_BYTES);
  talstm_kernel<<<1024, 1024, LDS_BYTES, stream>>>(inp, t, hx, cx, bih, bhh, bd, wp, out);
}

// Round 4
// 148.584 us; speedup vs baseline: 4.3847x; 1.1880x over previous
//
#include <hip/hip_runtime.h>

typedef _Float16 half8 __attribute__((ext_vector_type(8)));
typedef float    f32x4 __attribute__((ext_vector_type(4)));

#define LDS_BYTES (131072 + 256)   // A: 4 sections x 32 KiB fragment-major + t tile

__device__ __forceinline__ float rcpf(float x) { return __builtin_amdgcn_rcpf(x); }
__device__ __forceinline__ float sigf(float x)  { return rcpf(1.0f + __expf(-x)); }
__device__ __forceinline__ float tanhf_(float x){ return 1.0f - 2.0f * rcpf(1.0f + __expf(2.0f * x)); }

// ---------------- prepack: fp32 weights -> f16 MFMA-fragment granules in ws ----------------
// Gate granules (1 MiB @ wp+0): id = ((g*16 + h>>4)*16 + kslice), 1 KiB each.
//   Lane l reads byte l*16: element e = W[g*256 + (h0 + (l&15))][ks*32 + (l>>4)*8 + e]
//   (K = 512 = [Wih | Whh]).
// Decomp granules (128 KiB @ wp+1MiB): id = ((h>>4)*8 + kslice), value = Wd[k][h] (f16 hi;
//   lo correction comes from splitting cx, reusing the SAME B fragment for both passes).
__global__ __launch_bounds__(512) void prepack_kernel(
    const float* __restrict__ wih, const float* __restrict__ whh,
    const float* __restrict__ wd, char* __restrict__ wp)
{
  int idx = blockIdx.x * 512 + threadIdx.x;
  if (idx < 65536) {                       // gates: 8 consecutive k per thread
    int n  = idx >> 6;                     // 0..1023 = g*256 + h
    int k8 = (idx & 63) << 3;              // 0..504
    const float* src = (k8 < 256) ? (wih + n * 256 + k8) : (whh + n * 256 + (k8 - 256));
    f32x4 v0 = *(const f32x4*)src;
    f32x4 v1 = *(const f32x4*)(src + 4);
    half8 hv;
#pragma unroll
    for (int e = 0; e < 4; ++e) { hv[e] = (_Float16)v0[e]; hv[e + 4] = (_Float16)v1[e]; }
    int g = n >> 8, h = n & 255;
    int gran = (((g << 4) + (h >> 4)) << 4) + (k8 >> 5);
    int lane = (h & 15) + (((k8 >> 3) & 3) << 4);
    *(half8*)(wp + (gran << 10) + (lane << 4)) = hv;
  } else {                                 // decomp: scalar (coalesced reads over h)
    int i2 = idx - 65536;
    int h = i2 & 255, k = i2 >> 8;
    float v = wd[k * 256 + h];
    int gran = ((h >> 4) << 3) + (k >> 5);
    int lane = (h & 15) + (((k >> 3) & 3) << 4);
    *(_Float16*)(wp + (1 << 20) + (gran << 10) + (lane << 4) + ((k & 7) << 1)) = (_Float16)v;
  }
}

// ---------------- fused TA-LSTM cell ----------------
// Block: 1024 thr (16 waves), tile = 64 rows x FULL 256 h -> A read once from HBM.
// LDS: A in MFMA-FRAGMENT-MAJOR order: 4 sections (input|hx|cx_hi|cx_lo) x 32 granules.
//   Granule (sec, m, s) = 1 KiB: lane l's 16B = rows m*16+(l&15), k = s*32+(l>>4)*8..+8.
//   -> every ds_read/ds_write is 64 lanes x 16B linear within ONE granule: conflict-free,
//      immediate-offset addressable. ONE barrier; waves then stream W fragments from L2
//   with explicit depth-1 prefetch. Wave w owns 64 rows x 16 h. acc = 80 AGPR.
__global__ __launch_bounds__(1024, 4) void talstm_kernel(
    const float* __restrict__ inp, const float* __restrict__ tt,
    const float* __restrict__ hx,  const float* __restrict__ cx,
    const float* __restrict__ bih, const float* __restrict__ bhh,
    const float* __restrict__ bd,  const char* __restrict__ wp,
    float* __restrict__ out)
{
  extern __shared__ __align__(16) char smem[];
  float* tsh = (float*)(smem + 131072);
  const int tid  = threadIdx.x;
  const int lane = tid & 63;
  const int w    = __builtin_amdgcn_readfirstlane(tid >> 6);   // wave id = h-slice (0..15)
  const int rbase = blockIdx.x << 6;       // 64 rows/block

  // ---- stage A (once), fragment-major ----
  const int l15 = lane & 15;
  const int kq8 = (lane >> 4) << 3;        // k sub-offset within granule: 0,8,16,24
  const int laneB = lane << 4;

  if (w < 8) {                             // waves 0-3: input, 4-7: hx  (8 granules each)
    const float* src = (w < 4) ? inp : hx;
    char* dst = smem + ((w < 4) ? 0 : 32768);
#pragma unroll
    for (int i = 0; i < 8; ++i) {
      int m = w & 3, s = i;                // granule (m = w&3, s = i) covers gi = (w&3)*8+i
      const float* p = src + (size_t)(rbase + (m << 4) + l15) * 256 + (s << 5) + kq8;
      f32x4 v0 = *(const f32x4*)p;
      f32x4 v1 = *(const f32x4*)(p + 4);
      half8 hv;
#pragma unroll
      for (int e = 0; e < 4; ++e) { hv[e] = (_Float16)v0[e]; hv[e + 4] = (_Float16)v1[e]; }
      *(half8*)(dst + (((m << 3) + s) << 10) + laneB) = hv;
    }
  } else {                                 // waves 8-15: cx -> hi + lo granule pairs
#pragma unroll
    for (int i = 0; i < 4; ++i) {
      int gi = ((w & 7) << 2) + i;         // 0..31
      int m = gi >> 3, s = gi & 7;
      const float* p = cx + (size_t)(rbase + (m << 4) + l15) * 256 + (s << 5) + kq8;
      f32x4 v0 = *(const f32x4*)p;
      f32x4 v1 = *(const f32x4*)(p + 4);
      half8 hv, lv;
#pragma unroll
      for (int e = 0; e < 4; ++e) {
        hv[e]     = (_Float16)v0[e]; lv[e]     = (_Float16)(v0[e] - (float)hv[e]);
        hv[e + 4] = (_Float16)v1[e]; lv[e + 4] = (_Float16)(v1[e] - (float)hv[e + 4]);
      }
      *(half8*)(smem + 65536 + (gi << 10) + laneB) = hv;
      *(half8*)(smem + 98304 + (gi << 10) + laneB) = lv;
    }
  }
  if (tid < 64) tsh[tid] = tt[rbase + tid];
  __syncthreads();

  // ---- main compute: W fragments from L2 (prefetched), A fragments from LDS (imm offs) ----
  f32x4 acc[4][4];                         // [gate][m-strip]
  f32x4 accd[4];                           // [m-strip]
  const f32x4 fz = {0.f, 0.f, 0.f, 0.f};
#pragma unroll
  for (int g = 0; g < 4; ++g)
#pragma unroll
    for (int m = 0; m < 4; ++m) acc[g][m] = fz;
#pragma unroll
  for (int m = 0; m < 4; ++m) accd[m] = fz;

  const char* a0 = smem + laneB;           // gates sections (0..64 KiB)
  const char* a1 = smem + 65536 + laneB;   // cx sections
  const char* wg  = wp + (w << 14);        // gate g at +g*256 KiB, s at +s KiB
  const char* wdd = wp + (1 << 20) + (w << 13);

  half8 nb0 = *(const half8*)(wg             + laneB);
  half8 nb1 = *(const half8*)(wg + (1 << 18) + laneB);
  half8 nb2 = *(const half8*)(wg + (2 << 18) + laneB);
  half8 nb3 = *(const half8*)(wg + (3 << 18) + laneB);

#pragma unroll
  for (int s = 0; s < 16; ++s) {           // gates: K = 512
    half8 b0 = nb0, b1 = nb1, b2 = nb2, b3 = nb3;
    if (s < 15) {
      nb0 = *(const half8*)(wg + ((s + 1) << 10)             + laneB);
      nb1 = *(const half8*)(wg + ((s + 1) << 10) + (1 << 18) + laneB);
      nb2 = *(const half8*)(wg + ((s + 1) << 10) + (2 << 18) + laneB);
      nb3 = *(const half8*)(wg + ((s + 1) << 10) + (3 << 18) + laneB);
    }
    const int so = ((s >> 3) << 15) + ((s & 7) << 10);
#pragma unroll
    for (int m = 0; m < 4; ++m) {
      half8 a = *(const half8*)(a0 + so + (m << 13));
      acc[0][m] = __builtin_amdgcn_mfma_f32_16x16x32_f16(a, b0, acc[0][m], 0, 0, 0);
      acc[1][m] = __builtin_amdgcn_mfma_f32_16x16x32_f16(a, b1, acc[1][m], 0, 0, 0);
      acc[2][m] = __builtin_amdgcn_mfma_f32_16x16x32_f16(a, b2, acc[2][m], 0, 0, 0);
      acc[3][m] = __builtin_amdgcn_mfma_f32_16x16x32_f16(a, b3, acc[3][m], 0, 0, 0);
    }
  }

  half8 nbd = *(const half8*)(wdd + laneB);
#pragma unroll
  for (int s = 0; s < 8; ++s) {            // decomp: K = 256, hi+lo share the B frag
    half8 b = nbd;
    if (s < 7) nbd = *(const half8*)(wdd + ((s + 1) << 10) + laneB);
#pragma unroll
    for (int m = 0; m < 4; ++m) {
      half8 ah = *(const half8*)(a1 + (m << 13) + (s << 10));
      half8 al = *(const half8*)(a1 + 32768 + (m << 13) + (s << 10));
      accd[m] = __builtin_amdgcn_mfma_f32_16x16x32_f16(ah, b, accd[m], 0, 0, 0);
      accd[m] = __builtin_amdgcn_mfma_f32_16x16x32_f16(al, b, accd[m], 0, 0, 0);
    }
  }

  // ---- epilogue (division-free) ----
  const int er = (lane >> 4) << 2;         // C/D row within strip = er + e
  const int h  = (w << 4) + l15;
  const float bi  = bih[h]       + bhh[h];
  const float bfg = bih[256 + h] + bhh[256 + h];
  const float bg  = bih[512 + h] + bhh[512 + h];
  const float bo  = bih[768 + h] + bhh[768 + h];
  const float bdv = bd[h];
  // cx fragment read offsets: h fixed per thread
  const int hoff = ((w >> 1) << 10) + ((((w & 1) << 1) + (l15 >> 3)) << 8) + ((l15 & 7) << 1);
#pragma unroll
  for (int m = 0; m < 4; ++m) {
    float* po = out + (size_t)(rbase + (m << 4) + er) * 256 + h;
    const char* chp = smem + 65536 + (m << 13) + (er << 4) + hoff;
#pragma unroll
    for (int e = 0; e < 4; ++e) {
      const int rl = (m << 4) + er + e;
      const float tv = tsh[rl];
      const float T  = (tv != 0.0f) ? rcpf(tv) : 0.0f;
      const float cxv = (float)*(const _Float16*)(chp + (e << 4))
                      + (float)*(const _Float16*)(chp + 32768 + (e << 4));
      const float gi  = sigf  (acc[0][m][e] + bi);
      const float gf  = sigf  (acc[1][m][e] + bfg);
      const float gg  = tanhf_(acc[2][m][e] + bg);
      const float go  = sigf  (acc[3][m][e] + bo);
      const float cst = tanhf_(accd[m][e] + bdv);
      const float cxa = cxv - cst + T * cst;
      const float cy  = gf * cxa + gi * gg;
      const float hy  = go * tanhf_(cy);
      po[(size_t)e * 256]               = hy;
      po[16777216ull + (size_t)e * 256] = cy;
    }
  }
}

extern "C" void kernel_launch(void* const* d_in, const int* in_sizes, int n_in,
                              void* d_out, int out_size, void* d_ws, size_t ws_size,
                              hipStream_t stream) {
  const float* inp = (const float*)d_in[0];
  const float* t   = (const float*)d_in[1];
  const float* hx  = (const float*)d_in[2];
  const float* cx  = (const float*)d_in[3];
  const float* wih = (const float*)d_in[4];
  const float* whh = (const float*)d_in[5];
  const float* bih = (const float*)d_in[6];
  const float* bhh = (const float*)d_in[7];
  const float* wd  = (const float*)d_in[8];
  const float* bd  = (const float*)d_in[9];
  float* out = (float*)d_out;
  char* wp = (char*)d_ws;   // 1.125 MiB: 1 MiB gate granules + 128 KiB decomp granules

  prepack_kernel<<<256, 512, 0, stream>>>(wih, whh, wd, wp);

  hipFuncSetAttribute((const void*)talstm_kernel,
                      hipFuncAttributeMaxDynamicSharedMemorySize, LDS_BYTES);
  talstm_kernel<<<1024, 1024, LDS_BYTES, stream>>>(inp, t, hx, cx, bih, bhh, bd, wp, out);
}